// Round 1
// baseline (83.282 us; speedup 1.0000x reference)
//
#include <hip/hip_runtime.h>

// Problem constants
constexpr int NROWS     = 32;
constexpr int HW        = 768 * 768;        // 589824 pixels per image
constexpr int CHUNKS    = 16;               // chunks per row in main pass
constexpr int CHUNK_PIX = HW / CHUNKS;      // 36864
constexpr int NB        = 4096;             // histogram buckets (float bits >> 19)
constexpr int THREADS   = 256;

// Workspace layout (bytes)
constexpr size_t OFF_ROWPART = 0;                                  // float [NROWS*CHUNKS]
constexpr size_t OFF_POSCNT  = 2048;                               // uint  [NROWS]
constexpr size_t OFF_ROWC    = 2304;                               // double[NROWS]
constexpr size_t OFF_ROWTOT  = 2560;                               // double[NROWS]
constexpr size_t OFF_HIST    = 4096;                               // uint  [NROWS*NB]
constexpr size_t OFF_POSHIST = OFF_HIST + (size_t)NROWS * NB * 4;  // uint  [NROWS*NB]
constexpr size_t WS_USED     = OFF_POSHIST + (size_t)NROWS * NB * 4;

// Pass 1: per (row, chunk) block — compute CE, accumulate row CE-sum partial,
// positive count, and 4096-bucket histograms (all / positives) of CE values.
__global__ __launch_bounds__(THREADS) void ce_hist_kernel(
    const float* __restrict__ logits, const int* __restrict__ targets,
    float* __restrict__ rowpart, unsigned* __restrict__ poscnt,
    unsigned* __restrict__ hist, unsigned* __restrict__ poshist)
{
    __shared__ unsigned lh[NB];
    __shared__ unsigned lph[NB];
    __shared__ float    redf[THREADS / 64];
    __shared__ unsigned redi[THREADS / 64];

    const int blk   = blockIdx.x;
    const int row   = blk / CHUNKS;
    const int chunk = blk % CHUNKS;

    for (int b = threadIdx.x; b < NB; b += THREADS) { lh[b] = 0u; lph[b] = 0u; }
    __syncthreads();

    const float* x0 = logits + (size_t)row * 2 * HW + (size_t)chunk * CHUNK_PIX;
    const float* x1 = x0 + HW;
    const int*   tp = targets + (size_t)row * HW + (size_t)chunk * CHUNK_PIX;

    float    lsum = 0.f;
    unsigned lpos = 0u;

    for (int p = threadIdx.x * 4; p < CHUNK_PIX; p += THREADS * 4) {
        float4 a0 = *(const float4*)(x0 + p);
        float4 a1 = *(const float4*)(x1 + p);
        int4   t4 = *(const int4*)(tp + p);
        const float* v0 = (const float*)&a0;
        const float* v1 = (const float*)&a1;
        const int*   tv = (const int*)&t4;
#pragma unroll
        for (int j = 0; j < 4; ++j) {
            const int   t = tv[j];
            const float m = t ? (v1[j] - v0[j]) : (v0[j] - v1[j]);
            // ce = log(1 + exp(-m)), numerically stable
            const float ce = fmaxf(-m, 0.f) + log1pf(__expf(-fabsf(m)));
            lsum += ce;
            lpos += (unsigned)t;
            unsigned key = __float_as_uint(ce) >> 19;   // monotone for ce >= 0
            if (key > NB - 1) key = NB - 1;
            atomicAdd(&lh[key], 1u);
            if (t) atomicAdd(&lph[key], 1u);
        }
    }

    // wave reduce
    for (int o = 32; o > 0; o >>= 1) {
        lsum += __shfl_down(lsum, o);
        lpos += __shfl_down(lpos, o);
    }
    const int wid  = threadIdx.x >> 6;
    const int lane = threadIdx.x & 63;
    if (lane == 0) { redf[wid] = lsum; redi[wid] = lpos; }
    __syncthreads();   // also orders all LDS histogram atomics before flush

    if (threadIdx.x == 0) {
        float s = 0.f; unsigned pc = 0u;
        for (int w = 0; w < THREADS / 64; ++w) { s += redf[w]; pc += redi[w]; }
        rowpart[row * CHUNKS + chunk] = s;            // deterministic partial
        atomicAdd(&poscnt[row], pc);                  // integer atomic: deterministic
    }

    // flush LDS histograms (most buckets are zero — skip them)
    for (int b = threadIdx.x; b < NB; b += THREADS) {
        unsigned v = lh[b];
        if (v) atomicAdd(&hist[(size_t)row * NB + b], v);
        unsigned w = lph[b];
        if (w) atomicAdd(&poshist[(size_t)row * NB + b], w);
    }
}

// Pass 2: one block per row — find top-k threshold bucket from the histogram,
// count positives above it, proportionally split the threshold bucket.
// rowC[row] = |mask_row| (as double), rowtot[row] = sum of CE over the row.
__global__ __launch_bounds__(256) void select_kernel(
    const unsigned* __restrict__ hist, const unsigned* __restrict__ poshist,
    const unsigned* __restrict__ poscnt, const float* __restrict__ rowpart,
    double* __restrict__ rowC, double* __restrict__ rowtot)
{
    __shared__ unsigned lh[NB];
    __shared__ unsigned lph[NB];
    __shared__ unsigned segsum[256];
    __shared__ unsigned segsuf[256];
    __shared__ int      s_tb;
    __shared__ unsigned s_cgt;
    __shared__ unsigned s_posgt;

    const int row = blockIdx.x;
    const int tid = threadIdx.x;

    if (tid == 0) { s_posgt = 0u; s_tb = -1; s_cgt = 0u; }
    for (int b = tid; b < NB; b += 256) {
        lh[b]  = hist[(size_t)row * NB + b];
        lph[b] = poshist[(size_t)row * NB + b];
    }
    __syncthreads();

    const unsigned pos = poscnt[row];
    const unsigned k   = min(pos, (unsigned)HW - pos);

    // Each thread owns 16 buckets; thread 0 owns the TOP 16 (descending segments).
    const int base = NB - 16 * (tid + 1);
    unsigned ssum = 0u;
#pragma unroll
    for (int j = 0; j < 16; ++j) ssum += lh[base + j];
    segsum[tid] = ssum;
    __syncthreads();

    if (tid == 0) {
        unsigned c = 0u;
        for (int t = 0; t < 256; ++t) { segsuf[t] = c; c += segsum[t]; }
    }
    __syncthreads();

    if (k > 0) {
        const unsigned above = segsuf[tid];
        if (above < k && above + ssum >= k) {      // exactly one thread matches
            unsigned cum = above;
            for (int b = base + 15; b >= base; --b) {
                const unsigned nv = cum + lh[b];
                if (nv >= k) { s_tb = b; s_cgt = cum; break; }
                cum = nv;
            }
        }
    }
    __syncthreads();

    const int tb = s_tb;
    unsigned mypos = 0u;
    if (tb >= 0) {
#pragma unroll
        for (int j = 0; j < 16; ++j) {
            const int b = base + j;
            if (b > tb) mypos += lph[b];
        }
    }
    for (int o = 32; o > 0; o >>= 1) mypos += __shfl_down(mypos, o);
    if ((tid & 63) == 0) atomicAdd(&s_posgt, mypos);
    __syncthreads();

    if (tid == 0) {
        double Cr = 0.0;
        if (k > 0 && tb >= 0) {
            const unsigned rneed = k - s_cgt;          // 1..lh[tb]
            const unsigned hb = lh[tb], phb = lph[tb];
            const double P = (double)s_posgt +
                             (hb ? (double)rneed * (double)phb / (double)hb : 0.0);
            Cr = 2.0 * (double)k - P;                  // |A ∪ B|
        }
        rowC[row] = Cr;
        double s = 0.0;
        for (int c = 0; c < CHUNKS; ++c) s += (double)rowpart[row * CHUNKS + c];
        rowtot[row] = s;
    }
}

// Pass 3: final scalar.  out = ((nL - C)*r0 + C*r1) / nL
__global__ void final_kernel(const double* __restrict__ rowC,
                             const double* __restrict__ rowtot,
                             float* __restrict__ out)
{
    double C = 0.0;
    for (int r = 0; r < NROWS; ++r) C += rowC[r];
    const double nL = (double)NROWS * (double)HW;
    const double r0 = rowtot[0] / (double)HW;
    const double r1 = rowtot[1] / (double)HW;
    out[0] = (float)(((nL - C) * r0 + C * r1) / nL);
}

extern "C" void kernel_launch(void* const* d_in, const int* in_sizes, int n_in,
                              void* d_out, int out_size, void* d_ws, size_t ws_size,
                              hipStream_t stream) {
    const float* logits  = (const float*)d_in[0];
    const int*   targets = (const int*)d_in[1];
    float*       out     = (float*)d_out;
    char*        ws      = (char*)d_ws;

    hipMemsetAsync(ws, 0, WS_USED, stream);

    ce_hist_kernel<<<NROWS * CHUNKS, THREADS, 0, stream>>>(
        logits, targets,
        (float*)(ws + OFF_ROWPART), (unsigned*)(ws + OFF_POSCNT),
        (unsigned*)(ws + OFF_HIST), (unsigned*)(ws + OFF_POSHIST));

    select_kernel<<<NROWS, 256, 0, stream>>>(
        (const unsigned*)(ws + OFF_HIST), (const unsigned*)(ws + OFF_POSHIST),
        (const unsigned*)(ws + OFF_POSCNT), (const float*)(ws + OFF_ROWPART),
        (double*)(ws + OFF_ROWC), (double*)(ws + OFF_ROWTOT));

    final_kernel<<<1, 1, 0, stream>>>(
        (const double*)(ws + OFF_ROWC), (const double*)(ws + OFF_ROWTOT), out);
}

// Round 2
// 56.305 us; speedup vs baseline: 1.4791x; 1.4791x over previous
//
#include <hip/hip_runtime.h>

// Problem constants
constexpr int NROWS     = 32;
constexpr int HW        = 768 * 768;        // 589824 pixels per image
constexpr int CHUNKS    = 64;               // chunks per row in main pass
constexpr int CHUNK_PIX = HW / CHUNKS;      // 9216
constexpr int NB        = 4096;             // histogram buckets (float bits >> 19)
constexpr int THREADS   = 256;

// Workspace layout (bytes)
constexpr size_t OFF_ROWPART = 0;                                  // float [NROWS*CHUNKS] = 8 KB
constexpr size_t OFF_ROWC    = 8192;                               // double[NROWS]
constexpr size_t OFF_ROWTOT  = 8448;                               // double[NROWS]
constexpr size_t OFF_HIST    = 10240;                              // uint  [NROWS*NB]
constexpr size_t OFF_POSHIST = OFF_HIST + (size_t)NROWS * NB * 4;  // uint  [NROWS*NB]
constexpr size_t WS_USED     = OFF_POSHIST + (size_t)NROWS * NB * 4;

// Pass 1: per (row, chunk) block — compute ce2 = ce/ln2 (monotone in ce),
// accumulate row ce2-sum partial and a packed histogram (low16 = all count,
// high16 = positives count) over 4096 float-bit buckets.
__global__ __launch_bounds__(THREADS) void ce_hist_kernel(
    const float* __restrict__ logits, const int* __restrict__ targets,
    float* __restrict__ rowpart,
    unsigned* __restrict__ hist, unsigned* __restrict__ poshist)
{
    __shared__ unsigned lh[NB];
    __shared__ float    redf[THREADS / 64];

    const int blk   = blockIdx.x;
    const int row   = blk / CHUNKS;
    const int chunk = blk % CHUNKS;

    for (int b = threadIdx.x; b < NB; b += THREADS) lh[b] = 0u;
    __syncthreads();

    const float* x0 = logits + (size_t)row * 2 * HW + (size_t)chunk * CHUNK_PIX;
    const float* x1 = x0 + HW;
    const int*   tp = targets + (size_t)row * HW + (size_t)chunk * CHUNK_PIX;

    constexpr float L2E = 1.4426950408889634f;
    float lsum = 0.f;

    for (int p = threadIdx.x * 4; p < CHUNK_PIX; p += THREADS * 4) {
        float4 a0 = *(const float4*)(x0 + p);
        float4 a1 = *(const float4*)(x1 + p);
        int4   t4 = *(const int4*)(tp + p);
        const float* v0 = (const float*)&a0;
        const float* v1 = (const float*)&a1;
        const int*   tv = (const int*)&t4;
#pragma unroll
        for (int j = 0; j < 4; ++j) {
            const unsigned t = (unsigned)tv[j];
            // margin m = x_target - x_other = (t ? -(d) : d), d = x0 - x1
            float u = (v0[j] - v1[j]) * L2E;                       // m * log2(e)
            u = __uint_as_float(__float_as_uint(u) ^ (t << 31));   // sign flip if t==1
            // ce2 = ce/ln2 = max(-u,0) + log2(1 + 2^-|u|)   (>= 0, monotone in ce)
            const float e2  = exp2f(-fabsf(u));
            const float ce2 = fmaxf(-u, 0.f) + __log2f(1.f + e2);
            lsum += ce2;
            unsigned key = __float_as_uint(ce2) >> 19;             // monotone for ce2 >= 0
            if (key > NB - 1) key = NB - 1;
            atomicAdd(&lh[key], 1u | (t << 16));                   // one packed atomic
        }
    }

    // wave reduce the ce2 sum
    for (int o = 32; o > 0; o >>= 1) lsum += __shfl_down(lsum, o);
    const int wid  = threadIdx.x >> 6;
    const int lane = threadIdx.x & 63;
    if (lane == 0) redf[wid] = lsum;
    __syncthreads();   // also orders all LDS histogram atomics before flush

    if (threadIdx.x == 0) {
        float s = 0.f;
        for (int w = 0; w < THREADS / 64; ++w) s += redf[w];
        rowpart[row * CHUNKS + chunk] = s;            // deterministic partial
    }

    // flush packed LDS histogram (skip zero buckets)
    for (int b = threadIdx.x; b < NB; b += THREADS) {
        const unsigned v = lh[b];
        if (v) {
            atomicAdd(&hist[(size_t)row * NB + b], v & 0xFFFFu);
            const unsigned hi = v >> 16;
            if (hi) atomicAdd(&poshist[(size_t)row * NB + b], hi);
        }
    }
}

// Pass 2: one block per row — positives count from poshist, top-k threshold
// bucket from the histogram, positives above it, proportional split of the
// threshold bucket.  rowC[row] = |mask_row|, rowtot[row] = sum ce2 over row.
__global__ __launch_bounds__(256) void select_kernel(
    const unsigned* __restrict__ hist, const unsigned* __restrict__ poshist,
    const float* __restrict__ rowpart,
    double* __restrict__ rowC, double* __restrict__ rowtot)
{
    __shared__ unsigned lh[NB];
    __shared__ unsigned lph[NB];
    __shared__ unsigned segsum[256];
    __shared__ unsigned segpsum[256];
    __shared__ unsigned segsuf[256];
    __shared__ int      s_tb;
    __shared__ unsigned s_cgt;
    __shared__ unsigned s_posgt;
    __shared__ unsigned s_pos;

    const int row = blockIdx.x;
    const int tid = threadIdx.x;

    for (int b = tid; b < NB; b += 256) {
        lh[b]  = hist[(size_t)row * NB + b];
        lph[b] = poshist[(size_t)row * NB + b];
    }
    __syncthreads();

    // Each thread owns 16 buckets; thread 0 owns the TOP 16 (descending segments).
    const int base = NB - 16 * (tid + 1);
    unsigned ssum = 0u, psum = 0u;
#pragma unroll
    for (int j = 0; j < 16; ++j) { ssum += lh[base + j]; psum += lph[base + j]; }
    segsum[tid]  = ssum;
    segpsum[tid] = psum;
    __syncthreads();

    if (tid == 0) {
        unsigned c = 0u, pc = 0u;
        for (int t = 0; t < 256; ++t) { segsuf[t] = c; c += segsum[t]; pc += segpsum[t]; }
        s_pos   = pc;
        s_tb    = -1;
        s_cgt   = 0u;
        s_posgt = 0u;
    }
    __syncthreads();

    const unsigned pos = s_pos;
    const unsigned k   = min(pos, (unsigned)HW - pos);

    if (k > 0) {
        const unsigned above = segsuf[tid];
        if (above < k && above + ssum >= k) {      // exactly one thread matches
            unsigned cum = above;
            for (int b = base + 15; b >= base; --b) {
                const unsigned nv = cum + lh[b];
                if (nv >= k) { s_tb = b; s_cgt = cum; break; }
                cum = nv;
            }
        }
    }
    __syncthreads();

    const int tb = s_tb;
    unsigned mypos = 0u;
    if (tb >= 0) {
#pragma unroll
        for (int j = 0; j < 16; ++j) {
            const int b = base + j;
            if (b > tb) mypos += lph[b];
        }
    }
    for (int o = 32; o > 0; o >>= 1) mypos += __shfl_down(mypos, o);
    if ((tid & 63) == 0) atomicAdd(&s_posgt, mypos);
    __syncthreads();

    if (tid == 0) {
        double Cr = 0.0;
        if (k > 0 && tb >= 0) {
            const unsigned rneed = k - s_cgt;          // 1..lh[tb]
            const unsigned hb = lh[tb], phb = lph[tb];
            const double P = (double)s_posgt +
                             (hb ? (double)rneed * (double)phb / (double)hb : 0.0);
            Cr = 2.0 * (double)k - P;                  // |A ∪ B|
        }
        rowC[row] = Cr;
        double s = 0.0;
        for (int c = 0; c < CHUNKS; ++c) s += (double)rowpart[row * CHUNKS + c];
        rowtot[row] = s;                               // ce2 domain (× ln2 at the end)
    }
}

// Pass 3: final scalar.  out = ((nL - C)*r0 + C*r1) / nL, r in ce (nat-log) units.
__global__ void final_kernel(const double* __restrict__ rowC,
                             const double* __restrict__ rowtot,
                             float* __restrict__ out)
{
    constexpr double LN2 = 0.6931471805599453;
    double C = 0.0;
    for (int r = 0; r < NROWS; ++r) C += rowC[r];
    const double nL = (double)NROWS * (double)HW;
    const double r0 = rowtot[0] / (double)HW * LN2;
    const double r1 = rowtot[1] / (double)HW * LN2;
    out[0] = (float)(((nL - C) * r0 + C * r1) / nL);
}

extern "C" void kernel_launch(void* const* d_in, const int* in_sizes, int n_in,
                              void* d_out, int out_size, void* d_ws, size_t ws_size,
                              hipStream_t stream) {
    const float* logits  = (const float*)d_in[0];
    const int*   targets = (const int*)d_in[1];
    float*       out     = (float*)d_out;
    char*        ws      = (char*)d_ws;

    // zero only the accumulated histograms
    hipMemsetAsync(ws + OFF_HIST, 0, WS_USED - OFF_HIST, stream);

    ce_hist_kernel<<<NROWS * CHUNKS, THREADS, 0, stream>>>(
        logits, targets,
        (float*)(ws + OFF_ROWPART),
        (unsigned*)(ws + OFF_HIST), (unsigned*)(ws + OFF_POSHIST));

    select_kernel<<<NROWS, 256, 0, stream>>>(
        (const unsigned*)(ws + OFF_HIST), (const unsigned*)(ws + OFF_POSHIST),
        (const float*)(ws + OFF_ROWPART),
        (double*)(ws + OFF_ROWC), (double*)(ws + OFF_ROWTOT));

    final_kernel<<<1, 1, 0, stream>>>(
        (const double*)(ws + OFF_ROWC), (const double*)(ws + OFF_ROWTOT), out);
}